// Round 2
// baseline (492.784 us; speedup 1.0000x reference)
//
#include <hip/hip_runtime.h>
#include <hip/hip_bf16.h>
#include <stdint.h>

// LSTM cell: gates = x@Wx^T + bx + h@Wh^T + bh ; i,f,g,o split; c=f*c_prev+i*g; h=o*tanh(c)
// B=4096, IN=2048, H=2048 -> fused GEMM M=4096, N=8192(packed), K=4096, bf16 MFMA.
//
// Weight rows packed as p = 64*(j>>4) + 16*gate + (j&15) so that each wave's 4
// N-fragments (16 cols each) are gates i,f,g,o of the SAME j-block -> epilogue
// is thread-local.

#define M_DIM 4096
#define N_PACK 8192
#define K_DIM 4096
#define H_DIM 2048

typedef __attribute__((ext_vector_type(8))) short bf16x8;
typedef __attribute__((ext_vector_type(4))) float f32x4;
typedef __attribute__((ext_vector_type(8))) unsigned short ushortx8;

__device__ __forceinline__ unsigned short f2bf(float f) {
    union { float f; uint32_t u; } v; v.f = f;
    uint32_t u = v.u;
    uint32_t r = (u + 0x7FFFu + ((u >> 16) & 1u)) >> 16;
    return (unsigned short)r;
}

__device__ __forceinline__ float fsigmoid(float x) { return 1.0f / (1.0f + __expf(-x)); }
__device__ __forceinline__ float ftanh(float x) { return 2.0f * fsigmoid(2.0f * x) - 1.0f; }

// ---- pack A = [x | h_prev] -> bf16 [4096][4096] row-major ----
__global__ __launch_bounds__(256) void pack_a(const float* __restrict__ x,
                                              const float* __restrict__ h,
                                              unsigned short* __restrict__ A) {
    int i = blockIdx.x * 256 + threadIdx.x;   // each handles 8 elems
    int e = i * 8;
    int row = e >> 12;           // K=4096 cols
    int col = e & 4095;
    const float* src = (col < H_DIM) ? (x + (size_t)row * H_DIM + col)
                                     : (h + (size_t)row * H_DIM + (col - H_DIM));
    float4 f0 = ((const float4*)src)[0];
    float4 f1 = ((const float4*)src)[1];
    ushortx8 o;
    o[0] = f2bf(f0.x); o[1] = f2bf(f0.y); o[2] = f2bf(f0.z); o[3] = f2bf(f0.w);
    o[4] = f2bf(f1.x); o[5] = f2bf(f1.y); o[6] = f2bf(f1.z); o[7] = f2bf(f1.w);
    *(ushortx8*)(A + e) = o;
}

// ---- pack W = gate-interleaved [Wx | Wh] -> bf16 [8192][4096] ----
__global__ __launch_bounds__(256) void pack_w(const float* __restrict__ Wx,
                                              const float* __restrict__ Wh,
                                              unsigned short* __restrict__ W) {
    int i = blockIdx.x * 256 + threadIdx.x;
    int e = i * 8;
    int p = e >> 12;             // packed row
    int k = e & 4095;
    int g  = (p >> 4) & 3;
    int j  = ((p >> 6) << 4) | (p & 15);
    int orig = g * H_DIM + j;    // row in original 4H x K weight
    const float* src = (k < H_DIM) ? (Wx + (size_t)orig * H_DIM + k)
                                   : (Wh + (size_t)orig * H_DIM + (k - H_DIM));
    float4 f0 = ((const float4*)src)[0];
    float4 f1 = ((const float4*)src)[1];
    ushortx8 o;
    o[0] = f2bf(f0.x); o[1] = f2bf(f0.y); o[2] = f2bf(f0.z); o[3] = f2bf(f0.w);
    o[4] = f2bf(f1.x); o[5] = f2bf(f1.y); o[6] = f2bf(f1.z); o[7] = f2bf(f1.w);
    *(ushortx8*)(W + (size_t)p * K_DIM + k) = o;
}

__device__ __forceinline__ void gload_lds16(const void* g, void* l) {
    __builtin_amdgcn_global_load_lds(
        (const __attribute__((address_space(1))) void*)g,
        (__attribute__((address_space(3))) void*)l, 16, 0, 0);
}

// ---- fused GEMM + LSTM epilogue ----
// 128x128 tile, BK=64, 256 threads (4 waves, 2x2 of 64x64), XOR-swizzled LDS.
__global__ __launch_bounds__(256, 2) void lstm_gemm(
        const unsigned short* __restrict__ A,   // [4096][4096] bf16
        const unsigned short* __restrict__ W,   // [8192][4096] bf16 (packed rows)
        const float* __restrict__ bx, const float* __restrict__ bh,
        const float* __restrict__ c_prev, float* __restrict__ out) {
    __shared__ unsigned short Asm[128 * 64];   // 16 KB
    __shared__ unsigned short Bsm[128 * 64];   // 16 KB

    const int tid  = threadIdx.x;
    const int wid  = tid >> 6;
    const int lane = tid & 63;
    const int bid  = blockIdx.x;
    const int bm   = bid & 31;     // 32 M-blocks
    const int bn   = bid >> 5;     // 64 N-blocks
    const int wr   = wid >> 1;     // 0..1
    const int wc   = wid & 1;      // 0..1

    f32x4 acc[4][4] = {};

    const char* Abase = (const char*)A + (size_t)(bm * 128) * (K_DIM * 2);
    const char* Wbase = (const char*)W + (size_t)(bn * 128) * (K_DIM * 2);

    // per-thread staging source geometry (linear LDS dest, pre-swizzled source)
    int srow[4], skbs[4];
    #pragma unroll
    for (int q = 0; q < 4; ++q) {
        int chunk = wid * 4 + q;
        int o = chunk * 1024 + lane * 16;
        int row = o >> 7;          // 128 B per LDS row (BK=64 bf16)
        int kb  = o & 127;
        srow[q] = row;
        skbs[q] = kb ^ ((row & 7) << 4);
    }

    for (int kt = 0; kt < K_DIM / 64; ++kt) {
        // ---- stage tile kt into LDS (linear dest, swizzled src) ----
        #pragma unroll
        for (int q = 0; q < 4; ++q) {
            int chunk = wid * 4 + q;
            const char* ga = Abase + (size_t)srow[q] * (K_DIM * 2) + kt * 128 + skbs[q];
            const char* gb = Wbase + (size_t)srow[q] * (K_DIM * 2) + kt * 128 + skbs[q];
            gload_lds16(ga, (char*)Asm + chunk * 1024);
            gload_lds16(gb, (char*)Bsm + chunk * 1024);
        }
        __syncthreads();

        // ---- compute: 2 x (8 ds_read_b128 + 16 MFMA) ----
        #pragma unroll
        for (int kk = 0; kk < 2; ++kk) {
            bf16x8 af[4], bfr[4];
            #pragma unroll
            for (int m = 0; m < 4; ++m) {
                int row = wr * 64 + m * 16 + (lane & 15);
                int cb  = (kk * 64 + ((lane >> 4) << 4)) ^ ((row & 7) << 4);
                af[m] = *(const bf16x8*)((const char*)Asm + row * 128 + cb);
            }
            #pragma unroll
            for (int n = 0; n < 4; ++n) {
                int row = wc * 64 + n * 16 + (lane & 15);
                int cb  = (kk * 64 + ((lane >> 4) << 4)) ^ ((row & 7) << 4);
                bfr[n] = *(const bf16x8*)((const char*)Bsm + row * 128 + cb);
            }
            #pragma unroll
            for (int m = 0; m < 4; ++m)
                #pragma unroll
                for (int n = 0; n < 4; ++n)
                    acc[m][n] = __builtin_amdgcn_mfma_f32_16x16x32_bf16(
                        af[m], bfr[n], acc[m][n], 0, 0, 0);
        }
        __syncthreads();
    }

    // ---- LSTM epilogue (thread-local: n-fragment == gate) ----
    const int jlo  = lane & 15;
    const int rgrp = lane >> 4;
    const int pb   = bn * 128 + wc * 64;
    const int j    = ((pb >> 6) << 4) + jlo;      // output column in [0,2048)

    const float bi  = bx[j]             + bh[j];
    const float bff = bx[H_DIM + j]     + bh[H_DIM + j];
    const float bg  = bx[2 * H_DIM + j] + bh[2 * H_DIM + j];
    const float bo  = bx[3 * H_DIM + j] + bh[3 * H_DIM + j];

    float* out_h = out;
    float* out_c = out + (size_t)M_DIM * H_DIM;

    #pragma unroll
    for (int m = 0; m < 4; ++m) {
        int row0 = bm * 128 + wr * 64 + m * 16 + rgrp * 4;
        #pragma unroll
        for (int r = 0; r < 4; ++r) {
            int row = row0 + r;
            float pi = acc[m][0][r] + bi;
            float pf = acc[m][1][r] + bff;
            float pg = acc[m][2][r] + bg;
            float po = acc[m][3][r] + bo;
            float i_ = fsigmoid(pi);
            float f_ = fsigmoid(pf);
            float g_ = ftanh(pg);
            float o_ = fsigmoid(po);
            float cp = c_prev[(size_t)row * H_DIM + j];
            float c  = f_ * cp + i_ * g_;
            float hh = o_ * ftanh(c);
            out_h[(size_t)row * H_DIM + j] = hh;
            out_c[(size_t)row * H_DIM + j] = c;
        }
    }
}

extern "C" void kernel_launch(void* const* d_in, const int* in_sizes, int n_in,
                              void* d_out, int out_size, void* d_ws, size_t ws_size,
                              hipStream_t stream) {
    const float* x      = (const float*)d_in[0];
    const float* h_prev = (const float*)d_in[1];
    const float* c_prev = (const float*)d_in[2];
    const float* Wx     = (const float*)d_in[3];
    const float* bx     = (const float*)d_in[4];
    const float* Wh     = (const float*)d_in[5];
    const float* bh     = (const float*)d_in[6];

    unsigned short* Acat = (unsigned short*)d_ws;                       // 32 MB
    unsigned short* Wp   = (unsigned short*)d_ws + (size_t)M_DIM * K_DIM; // 64 MB

    float* out = (float*)d_out;

    // pack A: 4096*4096 / 8 elems/thread / 256 = 8192 blocks
    pack_a<<<8192, 256, 0, stream>>>(x, h_prev, Acat);
    // pack W: 8192*4096 / 8 / 256 = 16384 blocks
    pack_w<<<16384, 256, 0, stream>>>(Wx, Wh, Wp);
    // GEMM: (4096/128) * (8192/128) = 32*64 = 2048 blocks
    lstm_gemm<<<2048, 256, 0, stream>>>(Acat, Wp, bx, bh, c_prev, out);
}

// Round 3
// 474.773 us; speedup vs baseline: 1.0379x; 1.0379x over previous
//
#include <hip/hip_runtime.h>
#include <hip/hip_bf16.h>
#include <stdint.h>

// LSTM cell: gates = x@Wx^T + bx + h@Wh^T + bh; i,f,g,o; c=f*c_prev+i*g; h=o*tanh(c)
// Fused GEMM M=4096, N=8192(gate-packed), K=4096, bf16 MFMA.
// 256x256 tile, BK=64, 8 waves, 8-phase counted-vmcnt schedule (T2+T3+T4+T5+T1).

#define M_DIM 4096
#define N_PACK 8192
#define K_DIM 4096
#define H_DIM 2048

typedef __attribute__((ext_vector_type(8))) short bf16x8;
typedef __attribute__((ext_vector_type(4))) float f32x4;
typedef __attribute__((ext_vector_type(8))) unsigned short ushortx8;

__device__ __forceinline__ unsigned short f2bf(float f) {
    union { float f; uint32_t u; } v; v.f = f;
    uint32_t u = v.u;
    uint32_t r = (u + 0x7FFFu + ((u >> 16) & 1u)) >> 16;
    return (unsigned short)r;
}

__device__ __forceinline__ float fsigmoid(float x) { return 1.0f / (1.0f + __expf(-x)); }
__device__ __forceinline__ float ftanh(float x) { return 2.0f * fsigmoid(2.0f * x) - 1.0f; }

// ---- pack A = [x | h_prev] -> bf16 [4096][4096] row-major ----
__global__ __launch_bounds__(256) void pack_a(const float* __restrict__ x,
                                              const float* __restrict__ h,
                                              unsigned short* __restrict__ A) {
    int i = blockIdx.x * 256 + threadIdx.x;
    int e = i * 8;
    int row = e >> 12;
    int col = e & 4095;
    const float* src = (col < H_DIM) ? (x + (size_t)row * H_DIM + col)
                                     : (h + (size_t)row * H_DIM + (col - H_DIM));
    float4 f0 = ((const float4*)src)[0];
    float4 f1 = ((const float4*)src)[1];
    ushortx8 o;
    o[0] = f2bf(f0.x); o[1] = f2bf(f0.y); o[2] = f2bf(f0.z); o[3] = f2bf(f0.w);
    o[4] = f2bf(f1.x); o[5] = f2bf(f1.y); o[6] = f2bf(f1.z); o[7] = f2bf(f1.w);
    *(ushortx8*)(A + e) = o;
}

// ---- pack W = gate-interleaved [Wx | Wh] -> bf16 [8192][4096] ----
__global__ __launch_bounds__(256) void pack_w(const float* __restrict__ Wx,
                                              const float* __restrict__ Wh,
                                              unsigned short* __restrict__ W) {
    int i = blockIdx.x * 256 + threadIdx.x;
    int e = i * 8;
    int p = e >> 12;
    int k = e & 4095;
    int g  = (p >> 4) & 3;
    int j  = ((p >> 6) << 4) | (p & 15);
    int orig = g * H_DIM + j;
    const float* src = (k < H_DIM) ? (Wx + (size_t)orig * H_DIM + k)
                                   : (Wh + (size_t)orig * H_DIM + (k - H_DIM));
    float4 f0 = ((const float4*)src)[0];
    float4 f1 = ((const float4*)src)[1];
    ushortx8 o;
    o[0] = f2bf(f0.x); o[1] = f2bf(f0.y); o[2] = f2bf(f0.z); o[3] = f2bf(f0.w);
    o[4] = f2bf(f1.x); o[5] = f2bf(f1.y); o[6] = f2bf(f1.z); o[7] = f2bf(f1.w);
    *(ushortx8*)(W + (size_t)p * K_DIM + k) = o;
}

__device__ __forceinline__ void gload_lds16(const void* g, void* l) {
    __builtin_amdgcn_global_load_lds(
        (const __attribute__((address_space(1))) void*)g,
        (__attribute__((address_space(3))) void*)l, 16, 0, 0);
}

#define BAR() __builtin_amdgcn_s_barrier()
#define LGKM0() asm volatile("s_waitcnt lgkmcnt(0)" ::: "memory")
#define VMCNT2() asm volatile("s_waitcnt vmcnt(2)" ::: "memory")
#define VMCNT0() asm volatile("s_waitcnt vmcnt(0)" ::: "memory")

// ---- fused GEMM + LSTM epilogue, 256x256 tile, 8-phase schedule ----
__global__ __launch_bounds__(512, 2) void lstm_gemm8(
        const unsigned short* __restrict__ A,   // [4096][4096] bf16
        const unsigned short* __restrict__ W,   // [8192][4096] bf16 gate-packed
        const float* __restrict__ bx, const float* __restrict__ bh,
        const float* __restrict__ c_prev, float* __restrict__ out) {
    // lds[buf][mat][32KB]: mat 0 = A-tile 256x64, mat 1 = B-tile 256x64
    __shared__ char lds[2][2][32768];

    const int tid  = threadIdx.x;          // 0..511
    const int wid  = tid >> 6;             // 0..7
    const int lane = tid & 63;
    const int wr   = wid >> 2;             // 0..1  (M half)
    const int wc   = wid & 3;              // 0..3  (N quarter)

    // XCD-aware swizzle (512 blocks, 512%8==0 -> simple form is bijective)
    const int swz = (blockIdx.x & 7) * 64 + (blockIdx.x >> 3);
    const int bm  = swz & 15;              // 16 M tiles
    const int bn  = swz >> 4;              // 32 N tiles

    const char* Ab = (const char*)A + (size_t)(bm * 256) * (K_DIM * 2);
    const char* Wb = (const char*)W + (size_t)(bn * 256) * (K_DIM * 2);

    // staging geometry: issue q (0..3) covers rows q*64+srow, 16B at swizzled col
    const int srow = tid >> 3;                                   // 0..63
    const int skb  = ((tid & 7) << 4) ^ ((srow & 7) << 4);       // involution

    auto stage_half = [&](int buf, int mat, int h, int kt) {
        const char* gb = mat ? Wb : Ab;
        #pragma unroll
        for (int qq = 0; qq < 2; ++qq) {
            int q = h * 2 + qq;
            const char* src = gb + (size_t)(q * 64 + srow) * (K_DIM * 2) + kt * 128 + skb;
            gload_lds16(src, &lds[buf][mat][q * 8192 + tid * 16]);
        }
    };

    f32x4 acc[8][4] = {};
    bf16x8 A0[4][2], A1[4][2], Bq[2][2];

    auto read_a = [&](int buf, int qm, bf16x8 (&ar)[4][2]) {
        #pragma unroll
        for (int mf = 0; mf < 4; ++mf) {
            int row = wr * 128 + (qm * 4 + mf) * 16 + (lane & 15);
            #pragma unroll
            for (int kk = 0; kk < 2; ++kk) {
                int cb = (kk * 64 + ((lane >> 4) << 4)) ^ ((row & 7) << 4);
                ar[mf][kk] = *(const bf16x8*)&lds[buf][0][row * 128 + cb];
            }
        }
    };
    auto read_b = [&](int buf, int qn) {
        #pragma unroll
        for (int nf = 0; nf < 2; ++nf) {
            int row = wc * 64 + (qn * 2 + nf) * 16 + (lane & 15);
            #pragma unroll
            for (int kk = 0; kk < 2; ++kk) {
                int cb = (kk * 64 + ((lane >> 4) << 4)) ^ ((row & 7) << 4);
                Bq[nf][kk] = *(const bf16x8*)&lds[buf][1][row * 128 + cb];
            }
        }
    };

#define MMA_Q(QM, QN, AR)                                                      \
    do {                                                                       \
        __builtin_amdgcn_s_setprio(1);                                         \
        _Pragma("unroll")                                                      \
        for (int mf = 0; mf < 4; ++mf) {                                       \
            _Pragma("unroll")                                                  \
            for (int nf = 0; nf < 2; ++nf) {                                   \
                _Pragma("unroll")                                              \
                for (int kk = 0; kk < 2; ++kk) {                               \
                    acc[(QM)*4+mf][(QN)*2+nf] =                                \
                        __builtin_amdgcn_mfma_f32_16x16x32_bf16(               \
                            AR[mf][kk], Bq[nf][kk],                            \
                            acc[(QM)*4+mf][(QN)*2+nf], 0, 0, 0);               \
                }                                                              \
            }                                                                  \
        }                                                                      \
        __builtin_amdgcn_s_setprio(0);                                         \
    } while (0)

    // ---- prologue: T0 full (buf0: Ah0,Ah1,Bh0,Bh1), T1 Ah0 (buf1) ----
    stage_half(0, 0, 0, 0); stage_half(0, 0, 1, 0);
    stage_half(0, 1, 0, 0); stage_half(0, 1, 1, 0);
    stage_half(1, 0, 0, 1);
    VMCNT2();        // oldest 8 loads = all of T0
    BAR();

    // ---- main loop: iteration = K-tiles (2i, 2i+1); stages run 2 tiles ahead
    for (int it = 0; it < 32; ++it) {
        const int t1   = 2 * it + 1;
        const bool last = (it == 31);

        // ph0: reads A0,B0 of buf0 (12); stage buf1 A-h1 (T t1)
        read_a(0, 0, A0); read_b(0, 0);
        stage_half(1, 0, 1, t1);
        BAR(); LGKM0(); MMA_Q(0, 0, A0); BAR();

        // ph1: read A1 (8); stage buf1 B-h0
        read_a(0, 1, A1);
        stage_half(1, 1, 0, t1);
        BAR(); LGKM0(); MMA_Q(1, 0, A1); BAR();

        // ph2: read B1 (4); stage buf1 B-h1
        read_b(0, 1);
        stage_half(1, 1, 1, t1);
        BAR(); LGKM0(); MMA_Q(0, 1, A0); BAR();

        // ph3: stage buf0 A-h0 (T t1+1); counted wait -> buf1 (T t1) complete
        if (!last) { stage_half(0, 0, 0, t1 + 1); VMCNT2(); }
        else       { VMCNT0(); }
        BAR(); LGKM0(); MMA_Q(1, 1, A1); BAR();

        // ph4: reads A0,B0 of buf1 (12); stage buf0 A-h1
        read_a(1, 0, A0); read_b(1, 0);
        if (!last) stage_half(0, 0, 1, t1 + 1);
        BAR(); LGKM0(); MMA_Q(0, 0, A0); BAR();

        // ph5: read A1 of buf1; stage buf0 B-h0
        read_a(1, 1, A1);
        if (!last) stage_half(0, 1, 0, t1 + 1);
        BAR(); LGKM0(); MMA_Q(1, 0, A1); BAR();

        // ph6: read B1 of buf1; stage buf0 B-h1
        read_b(1, 1);
        if (!last) stage_half(0, 1, 1, t1 + 1);
        BAR(); LGKM0(); MMA_Q(0, 1, A0); BAR();

        // ph7: stage buf1 A-h0 (T t1+2); counted wait -> buf0 (T t1+1) complete
        if (!last) { stage_half(1, 0, 0, t1 + 2); VMCNT2(); }
        else       { VMCNT0(); }
        BAR(); LGKM0(); MMA_Q(1, 1, A1); BAR();
    }

    // ---- LSTM epilogue (thread-local: n-fragment == gate) ----
    const int jlo  = lane & 15;
    const int rgrp = lane >> 4;
    const int j    = (bn * 4 + wc) * 16 + jlo;     // output column in [0,2048)

    const float bi  = bx[j]             + bh[j];
    const float bff = bx[H_DIM + j]     + bh[H_DIM + j];
    const float bg  = bx[2 * H_DIM + j] + bh[2 * H_DIM + j];
    const float bo  = bx[3 * H_DIM + j] + bh[3 * H_DIM + j];

    float* out_h = out;
    float* out_c = out + (size_t)M_DIM * H_DIM;

    #pragma unroll
    for (int m = 0; m < 8; ++m) {
        int row0 = bm * 256 + wr * 128 + m * 16 + rgrp * 4;
        #pragma unroll
        for (int r = 0; r < 4; ++r) {
            int row = row0 + r;
            float pi = acc[m][0][r] + bi;
            float pf = acc[m][1][r] + bff;
            float pg = acc[m][2][r] + bg;
            float po = acc[m][3][r] + bo;
            float i_ = fsigmoid(pi);
            float f_ = fsigmoid(pf);
            float g_ = ftanh(pg);
            float o_ = fsigmoid(po);
            float cp = c_prev[(size_t)row * H_DIM + j];
            float c  = f_ * cp + i_ * g_;
            float hh = o_ * ftanh(c);
            out_h[(size_t)row * H_DIM + j] = hh;
            out_c[(size_t)row * H_DIM + j] = c;
        }
    }
}

extern "C" void kernel_launch(void* const* d_in, const int* in_sizes, int n_in,
                              void* d_out, int out_size, void* d_ws, size_t ws_size,
                              hipStream_t stream) {
    const float* x      = (const float*)d_in[0];
    const float* h_prev = (const float*)d_in[1];
    const float* c_prev = (const float*)d_in[2];
    const float* Wx     = (const float*)d_in[3];
    const float* bx     = (const float*)d_in[4];
    const float* Wh     = (const float*)d_in[5];
    const float* bh     = (const float*)d_in[6];

    unsigned short* Acat = (unsigned short*)d_ws;                         // 32 MB
    unsigned short* Wp   = (unsigned short*)d_ws + (size_t)M_DIM * K_DIM; // 64 MB

    float* out = (float*)d_out;

    pack_a<<<8192, 256, 0, stream>>>(x, h_prev, Acat);
    pack_w<<<16384, 256, 0, stream>>>(Wx, Wh, Wp);
    // GEMM: (4096/256) * (8192/256) = 16*32 = 512 blocks, 512 threads
    lstm_gemm8<<<512, 512, 0, stream>>>(Acat, Wp, bx, bh, c_prev, out);
}